// Round 11
// baseline (315.100 us; speedup 1.0000x reference)
//
#include <hip/hip_runtime.h>
#include <math.h>

#define N_NODES 32768
#define N_EDGES 262144
#define OUTC 54      // 16 emb + 38 msg
#define TPW  40      // tp row stride in floats (38 used, 16B-aligned)
#define TGRID 64     // d0 samples per bin (65 points incl. both ends)
#define TENT 384     // floats per table entry: 16 i * 24 padded cols

// ---------------- Kernel 1: node embeddings -----------------
__global__ __launch_bounds__(256) void node_emb_kernel(
    const float* __restrict__ x, const float* __restrict__ W1,
    const float* __restrict__ W2, float* __restrict__ out)
{
    int n = blockIdx.x * blockDim.x + threadIdx.x;
    if (n >= N_NODES) return;
    const float inv10 = 0.31622776601683794f;
    const float inv64 = 0.125f;

    float xr[10];
    #pragma unroll
    for (int i = 0; i < 10; ++i) xr[i] = x[n*10 + i];

    float t[64];
    #pragma unroll
    for (int k = 0; k < 64; ++k) {
        float acc = 0.f;
        #pragma unroll
        for (int i = 0; i < 10; ++i) acc = fmaf(xr[i], W1[i*64 + k], acc);
        t[k] = acc * inv10;
    }

    float e[16];
    #pragma unroll
    for (int j = 0; j < 16; ++j) e[j] = 0.f;
    #pragma unroll
    for (int k = 0; k < 64; ++k) {
        float tk = t[k];
        #pragma unroll
        for (int j = 0; j < 16; ++j) e[j] = fmaf(tk, W2[k*16 + j], e[j]);
    }
    #pragma unroll
    for (int j = 0; j < 16; ++j) out[n*OUTC + j] = e[j] * inv64;
}

// ---------------- CSR build -----------------
__global__ __launch_bounds__(256) void count_kernel(
    const int* __restrict__ ei, int* __restrict__ cnt)
{
    int e = blockIdx.x * blockDim.x + threadIdx.x;
    if (e < N_EDGES) atomicAdd(&cnt[ei[N_EDGES + e]], 1);
}

__global__ __launch_bounds__(1024) void scan_kernel(
    int* __restrict__ cursor, int* __restrict__ start)
{
    __shared__ int partial[1024];
    int tid = threadIdx.x;
    int base = tid * 32;
    int v[32];
    int s = 0;
    #pragma unroll
    for (int j = 0; j < 32; ++j) { v[j] = cursor[base + j]; s += v[j]; }
    partial[tid] = s;
    __syncthreads();
    for (int off = 1; off < 1024; off <<= 1) {
        int t = (tid >= off) ? partial[tid - off] : 0;
        __syncthreads();
        partial[tid] += t;
        __syncthreads();
    }
    int run = (tid > 0) ? partial[tid - 1] : 0;
    #pragma unroll
    for (int j = 0; j < 32; ++j) {
        start[base + j] = run;
        cursor[base + j] = run;
        run += v[j];
    }
    if (tid == 1023) start[N_NODES] = run;
}

// ---------------- Table build: W_eff[m][g][i][c] ------------------------
// T[(m*65+g)*384 + i*24 + c] = sc * sum_k h_k(m, g/64) * W2[k][widx(c,i)]
__global__ __launch_bounds__(256) void table_kernel(
    const float* __restrict__ Wt1, const float* __restrict__ Wt2,
    float* __restrict__ T)
{
    int entry = blockIdx.x;            // 0 .. 21*65-1
    int m = entry / 65;
    int g = entry - m * 65;
    float d0 = (float)g * (1.0f / TGRID);
    float d1 = d0 - 1.0f;
    int j0 = m - 1, j1 = m;
    const float sq20 = 4.47213595499958f;

    float f0 = 0.f, f1 = 0.f;
    if (j0 >= 0 && j0 < 20)
        f0 = 1.14136f * expf(2.0f - 1.0f/(1.0f + d0) - 1.0f/(1.0f - d0)) * sq20;
    if (j1 >= 0 && j1 < 20)
        f1 = 1.14136f * expf(2.0f - 1.0f/(1.0f + d1) - 1.0f/(1.0f - d1)) * sq20;
    j0 = j0 < 0 ? 0 : (j0 > 19 ? 19 : j0);
    j1 = j1 < 0 ? 0 : (j1 > 19 ? 19 : j1);

    __shared__ float h[64];
    int t = threadIdx.x;
    if (t < 64) {
        float a = fmaf(f0, Wt1[j0*64 + t], f1 * Wt1[j1*64 + t])
                  * 0.22360679774997896f;
        h[t] = 1.679177f * a / (1.0f + expf(-a));
    }
    __syncthreads();

    // sc = 1/8 (w norm) * 1/4 (inv) * 1/sqrt(8) (neighbor norm)
    const float sc = 0.011048543456039806f;
    for (int e2 = t; e2 < TENT; e2 += 256) {
        int i = e2 / 24;
        int c = e2 - i * 24;
        float v = 0.f;
        if (c < 22) {
            int widx = (c < 16) ? (i*16 + c)
                     : (c < 20) ? (256 + i*4 + (c - 16))
                                : (320 + i*2 + (c - 20));
            for (int k = 0; k < 64; ++k)
                v = fmaf(h[k], Wt2[k*352 + widx], v);
            v *= sc;
        }
        T[(size_t)entry * TENT + e2] = v;
    }
}

// ---------------- Kernel 3: per-edge lerp + contract, 4 lanes/edge -------
// Lane group of 4 handles one edge; lane ipart covers i in [ipart*4, +4).
// Intra-group table loads are consecutive float4s of the SAME row ->
// coalesced; 16 distinct rows per wave instead of 64. Partials combine
// via two group-local shfl_xor rounds.
__global__ __launch_bounds__(256) void edge_table_kernel4(
    const float* __restrict__ pos, const int* __restrict__ ei,
    const float* __restrict__ T, const float* __restrict__ outp,
    float* __restrict__ tp, int* __restrict__ cursor, int* __restrict__ elist)
{
    int t = threadIdx.x;
    int ipart = t & 3;
    int e = blockIdx.x * 64 + (t >> 2);

    int src = ei[e];
    int dst = ei[N_EDGES + e];

    if (ipart == 0) {
        int slot = atomicAdd(&cursor[dst], 1);
        elist[slot] = e;
    }

    float px = pos[dst*3+0] - pos[src*3+0];
    float py = pos[dst*3+1] - pos[src*3+1];
    float pz = pos[dst*3+2] - pos[src*3+2];
    float dist = sqrtf(px*px + py*py + pz*pz + 1e-12f);
    float rinv = 1.0f / dist;
    float ux = px*rinv, uy = py*rinv, uz = pz*rinv;

    float tt = dist * 4.2f;          // dist / (5/21)
    bool inrange = (tt < 21.0f);     // uniform within the 4-lane group

    float vals[38];
    #pragma unroll
    for (int c = 0; c < 38; ++c) vals[c] = 0.f;

    if (inrange) {
        int m  = (int)tt;                // 0..20
        float d0 = tt - (float)m;
        float gf = d0 * (float)TGRID;
        int g0 = (int)gf; if (g0 > TGRID-1) g0 = TGRID-1;
        float fr = gf - (float)g0;

        const float4* r0 = (const float4*)
            (T + (size_t)(m*65 + g0) * TENT + ipart*4*24);
        const float4* r1 = r0 + (TENT/4);    // next d0 grid point

        float z[4];
        #pragma unroll
        for (int j = 0; j < 4; ++j)
            z[j] = outp[src*OUTC + ipart*4 + j];

        float a[24];
        #pragma unroll
        for (int c = 0; c < 24; ++c) a[c] = 0.f;

        #pragma unroll
        for (int i = 0; i < 4; ++i) {
            float zi = z[i];
            #pragma unroll
            for (int q = 0; q < 6; ++q) {
                float4 v0 = r0[i*6 + q];
                float4 v1 = r1[i*6 + q];
                // fused per-element lerp, then contract with z
                float w;
                w = fmaf(fr, v1.x - v0.x, v0.x); a[q*4+0] = fmaf(zi, w, a[q*4+0]);
                w = fmaf(fr, v1.y - v0.y, v0.y); a[q*4+1] = fmaf(zi, w, a[q*4+1]);
                w = fmaf(fr, v1.z - v0.z, v0.z); a[q*4+2] = fmaf(zi, w, a[q*4+2]);
                w = fmaf(fr, v1.w - v0.w, v0.w); a[q*4+3] = fmaf(zi, w, a[q*4+3]);
            }
        }

        // group reduction: partners (xor 1, xor 2) stay inside the 4-lane
        // group, which shares the same `inrange` -> all partners active
        #pragma unroll
        for (int c = 0; c < 22; ++c) {
            float v = a[c];
            v += __shfl_xor(v, 1, 64);
            v += __shfl_xor(v, 2, 64);
            vals[c] = v;
        }

        const float s3  = 1.7320508075688772f;
        const float s15 = 3.872983346207417f;
        const float s5  = 2.23606797749979f;
        float sh1x = s3*ux, sh1y = s3*uy, sh1z = s3*uz;
        float sh2a = s15 * ux * uz;
        float sh2b = s15 * ux * uy;
        float sh2c = s5 * (uy*uy - 0.5f*(ux*ux + uz*uz));
        float sh2d = s15 * uy * uz;
        float sh2e = 0.5f * s15 * (uz*uz - ux*ux);

        // expand T first (consumes vals[20..21]), then V descending (16..19)
        #pragma unroll
        for (int u = 1; u >= 0; --u) {
            float v = vals[20 + u];
            vals[28 + u*5 + 0] = v * sh2a;
            vals[28 + u*5 + 1] = v * sh2b;
            vals[28 + u*5 + 2] = v * sh2c;
            vals[28 + u*5 + 3] = v * sh2d;
            vals[28 + u*5 + 4] = v * sh2e;
        }
        #pragma unroll
        for (int u = 3; u >= 0; --u) {
            float v = vals[16 + u];
            vals[16 + u*3 + 0] = v * sh1x;
            vals[16 + u*3 + 1] = v * sh1y;
            vals[16 + u*3 + 2] = v * sh1z;
        }
    }

    // cooperative write: lane ipart writes float4 q = ipart, ipart+4, ipart+8
    float* trow = tp + (size_t)e * TPW;
    #pragma unroll
    for (int q0 = 0; q0 < 3; ++q0) {
        int q = ipart + q0*4;
        if (q < 9)
            *reinterpret_cast<float4*>(trow + q*4) =
                make_float4(vals[q*4+0], vals[q*4+1], vals[q*4+2], vals[q*4+3]);
    }
    if (ipart == 0) { trow[36] = vals[36]; trow[37] = vals[37]; }
}

// ---------------- Kernel 4: gather segment-sum, SORTED (deterministic) ------
__global__ __launch_bounds__(256) void gather_sorted_kernel(
    const float* __restrict__ tp, const int* __restrict__ start,
    const int* __restrict__ elist, float* __restrict__ out)
{
    __shared__ int sb[4][128];
    __shared__ int so[4][128];
    int wave = threadIdx.x >> 6;
    int lane = threadIdx.x & 63;
    int n = blockIdx.x * 4 + wave;          // grid == N_NODES/4, always valid
    int s0 = start[n], s1 = start[n+1];
    int K = s1 - s0;
    bool small = (K <= 128);

    if (small) {
        for (int j = lane; j < K; j += 64) sb[wave][j] = elist[s0 + j];
    }
    __syncthreads();
    if (small) {
        for (int j = lane; j < K; j += 64) {
            int v = sb[wave][j];
            int r = 0;
            for (int q = 0; q < K; ++q) r += (sb[wave][q] < v);
            so[wave][r] = v;    // edge ids distinct -> r is a permutation
        }
    }
    __syncthreads();

    if (lane < 38) {
        float acc = 0.f;
        if (small) {
            for (int j = 0; j < K; ++j)
                acc += tp[(size_t)so[wave][j] * TPW + lane];
        } else {
            for (int j = s0; j < s1; ++j)
                acc += tp[(size_t)elist[j] * TPW + lane];
        }
        out[n*OUTC + 16 + lane] = acc;
    }
}

// ---------------- fallback (atomics) if ws too small -----------------
__global__ __launch_bounds__(256) void edge_kernel_atomic(
    const float* __restrict__ pos, const int* __restrict__ ei,
    const float* __restrict__ Wt1, const float* __restrict__ Wt2,
    float* out)
{
    int e = blockIdx.x * blockDim.x + threadIdx.x;
    if (e >= N_EDGES) return;
    int src = ei[e];
    int dst = ei[N_EDGES + e];
    float px = pos[dst*3+0] - pos[src*3+0];
    float py = pos[dst*3+1] - pos[src*3+1];
    float pz = pos[dst*3+2] - pos[src*3+2];
    float dist = sqrtf(px*px + py*py + pz*pz + 1e-12f);
    float rinv = 1.0f / dist;
    float ux = px*rinv, uy = py*rinv, uz = pz*rinv;
    const float step = 5.0f / 21.0f;
    float tt = dist / step;
    int m  = (int)floorf(tt);
    int j0 = m - 1, j1 = m;
    float d0 = tt - (float)m, d1 = d0 - 1.0f;
    const float sq20 = 4.47213595499958f;
    float f0 = 0.f, f1 = 0.f;
    if (j0 >= 0 && j0 < 20)
        f0 = 1.14136f * expf(2.0f - 1.0f/(1.0f + d0) - 1.0f/(1.0f - d0)) * sq20;
    if (j1 >= 0 && j1 < 20 && d1 > -1.0f)
        f1 = 1.14136f * expf(2.0f - 1.0f/(1.0f + d1) - 1.0f/(1.0f - d1)) * sq20;
    if (f0 == 0.f && f1 == 0.f) return;
    j0 = j0 < 0 ? 0 : (j0 > 19 ? 19 : j0);
    j1 = j1 < 0 ? 0 : (j1 > 19 ? 19 : j1);
    const float* w1a = Wt1 + j0*64;
    const float* w1b = Wt1 + j1*64;
    float z[16];
    #pragma unroll
    for (int i = 0; i < 16; ++i) z[i] = out[src*OUTC + i];
    const float rsq20 = 0.22360679774997896f;
    const float snorm = 1.679177f;
    float accS[16], accV[4], accT[2];
    #pragma unroll
    for (int u = 0; u < 16; ++u) accS[u] = 0.f;
    #pragma unroll
    for (int u = 0; u < 4; ++u) accV[u] = 0.f;
    #pragma unroll
    for (int u = 0; u < 2; ++u) accT[u] = 0.f;
    for (int k = 0; k < 64; ++k) {
        float a = fmaf(f0, w1a[k], f1 * w1b[k]) * rsq20;
        float hk = snorm * a / (1.0f + expf(-a));
        const float* row = Wt2 + k*352;
        float tmp[16];
        #pragma unroll
        for (int u = 0; u < 16; ++u) tmp[u] = 0.f;
        #pragma unroll
        for (int i = 0; i < 16; ++i) {
            float zi = z[i];
            #pragma unroll
            for (int u = 0; u < 16; ++u) tmp[u] = fmaf(zi, row[i*16 + u], tmp[u]);
        }
        #pragma unroll
        for (int u = 0; u < 16; ++u) accS[u] = fmaf(hk, tmp[u], accS[u]);
        float tv[4] = {0.f,0.f,0.f,0.f};
        #pragma unroll
        for (int i = 0; i < 16; ++i) {
            float zi = z[i];
            #pragma unroll
            for (int u = 0; u < 4; ++u) tv[u] = fmaf(zi, row[256 + i*4 + u], tv[u]);
        }
        #pragma unroll
        for (int u = 0; u < 4; ++u) accV[u] = fmaf(hk, tv[u], accV[u]);
        float tw[2] = {0.f,0.f};
        #pragma unroll
        for (int i = 0; i < 16; ++i) {
            float zi = z[i];
            #pragma unroll
            for (int u = 0; u < 2; ++u) tw[u] = fmaf(zi, row[320 + i*2 + u], tw[u]);
        }
        #pragma unroll
        for (int u = 0; u < 2; ++u) accT[u] = fmaf(hk, tw[u], accT[u]);
    }
    const float sc = 0.125f * 0.25f * 0.35355339059327373f;
    const float s3  = 1.7320508075688772f;
    const float s15 = 3.872983346207417f;
    const float s5  = 2.23606797749979f;
    float sh1x = s3*ux, sh1y = s3*uy, sh1z = s3*uz;
    float sh2[5];
    sh2[0] = s15 * ux * uz;
    sh2[1] = s15 * ux * uy;
    sh2[2] = s5 * (uy*uy - 0.5f*(ux*ux + uz*uz));
    sh2[3] = s15 * uy * uz;
    sh2[4] = 0.5f * s15 * (uz*uz - ux*ux);
    float* orow = out + dst*OUTC + 16;
    #pragma unroll
    for (int u = 0; u < 16; ++u) atomicAdd(&orow[u], accS[u] * sc);
    #pragma unroll
    for (int u = 0; u < 4; ++u) {
        float v = accV[u] * sc;
        atomicAdd(&orow[16 + u*3 + 0], v * sh1x);
        atomicAdd(&orow[16 + u*3 + 1], v * sh1y);
        atomicAdd(&orow[16 + u*3 + 2], v * sh1z);
    }
    #pragma unroll
    for (int u = 0; u < 2; ++u) {
        float v = accT[u] * sc;
        #pragma unroll
        for (int mm = 0; mm < 5; ++mm)
            atomicAdd(&orow[28 + u*5 + mm], v * sh2[mm]);
    }
}

extern "C" void kernel_launch(void* const* d_in, const int* in_sizes, int n_in,
                              void* d_out, int out_size, void* d_ws, size_t ws_size,
                              hipStream_t stream) {
    const float* x   = (const float*)d_in[0];
    const float* pos = (const float*)d_in[1];
    const int*   ei  = (const int*)d_in[2];
    const float* We1 = (const float*)d_in[3];
    const float* We2 = (const float*)d_in[4];
    const float* Wt1 = (const float*)d_in[5];
    const float* Wt2 = (const float*)d_in[6];
    float* out = (float*)d_out;

    char* base = (char*)d_ws;
    size_t off = 0;
    float* tp = (float*)(base + off);       off += (size_t)N_EDGES * TPW * 4;
    float* T  = (float*)(base + off);       off += (size_t)21 * 65 * TENT * 4;  // 2.1 MB
    int* cursor = (int*)(base + off);       off += (size_t)N_NODES * 4;
    int* startp = (int*)(base + off);       off += (size_t)(N_NODES + 1) * 4;
    int* elist  = (int*)(base + off);       off += (size_t)N_EDGES * 4;
    size_t need = off;

    node_emb_kernel<<<N_NODES/256, 256, 0, stream>>>(x, We1, We2, out);

    if (ws_size >= need) {
        table_kernel<<<21*65, 256, 0, stream>>>(Wt1, Wt2, T);
        hipMemsetAsync(cursor, 0, (size_t)N_NODES * sizeof(int), stream);
        count_kernel<<<N_EDGES/256, 256, 0, stream>>>(ei, cursor);
        scan_kernel<<<1, 1024, 0, stream>>>(cursor, startp);
        edge_table_kernel4<<<N_EDGES/64, 256, 0, stream>>>(pos, ei, T, out,
                                                           tp, cursor, elist);
        gather_sorted_kernel<<<N_NODES/4, 256, 0, stream>>>(tp, startp, elist, out);
    } else {
        hipMemsetAsync(out, 0, (size_t)out_size * sizeof(float), stream);
        node_emb_kernel<<<N_NODES/256, 256, 0, stream>>>(x, We1, We2, out);
        edge_kernel_atomic<<<N_EDGES/256, 256, 0, stream>>>(pos, ei, Wt1, Wt2, out);
    }
}

// Round 12
// 299.542 us; speedup vs baseline: 1.0519x; 1.0519x over previous
//
#include <hip/hip_runtime.h>
#include <math.h>

#define N_NODES 32768
#define N_EDGES 262144
#define OUTC 54      // 16 emb + 38 msg
#define TPW  40      // tp row stride in floats (38 used, 16B-aligned)
#define TGRID 64     // d0 samples per bin (65 points incl. both ends)
#define TENT 384     // floats per table entry: 16 i * 24 padded cols
#define NBINS 1345   // 21*64 in-range bins + 1 out-of-range bin

// ---------------- Kernel 1: node embeddings -----------------
__global__ __launch_bounds__(256) void node_emb_kernel(
    const float* __restrict__ x, const float* __restrict__ W1,
    const float* __restrict__ W2, float* __restrict__ out)
{
    int n = blockIdx.x * blockDim.x + threadIdx.x;
    if (n >= N_NODES) return;
    const float inv10 = 0.31622776601683794f;
    const float inv64 = 0.125f;

    float xr[10];
    #pragma unroll
    for (int i = 0; i < 10; ++i) xr[i] = x[n*10 + i];

    float t[64];
    #pragma unroll
    for (int k = 0; k < 64; ++k) {
        float acc = 0.f;
        #pragma unroll
        for (int i = 0; i < 10; ++i) acc = fmaf(xr[i], W1[i*64 + k], acc);
        t[k] = acc * inv10;
    }

    float e[16];
    #pragma unroll
    for (int j = 0; j < 16; ++j) e[j] = 0.f;
    #pragma unroll
    for (int k = 0; k < 64; ++k) {
        float tk = t[k];
        #pragma unroll
        for (int j = 0; j < 16; ++j) e[j] = fmaf(tk, W2[k*16 + j], e[j]);
    }
    #pragma unroll
    for (int j = 0; j < 16; ++j) out[n*OUTC + j] = e[j] * inv64;
}

// ---------------- bin function (shared by count & fill) ------------------
__device__ __forceinline__ int edge_bin(const float* __restrict__ pos,
                                        int src, int dst)
{
    float px = pos[dst*3+0] - pos[src*3+0];
    float py = pos[dst*3+1] - pos[src*3+1];
    float pz = pos[dst*3+2] - pos[src*3+2];
    float dist = sqrtf(px*px + py*py + pz*pz + 1e-12f);
    float tt = dist * 4.2f;
    if (!(tt < 21.0f)) return NBINS - 1;     // out-of-range bin
    int m = (int)tt;
    float gf = (tt - (float)m) * (float)TGRID;
    int g0 = (int)gf; if (g0 > TGRID-1) g0 = TGRID-1;
    return m * TGRID + g0;
}

// ---------------- CSR counts: dst degree + table-row bin -----------------
__global__ __launch_bounds__(256) void count_both_kernel(
    const int* __restrict__ ei, const float* __restrict__ pos,
    int* __restrict__ cd, int* __restrict__ cb)
{
    int e = blockIdx.x * blockDim.x + threadIdx.x;
    if (e >= N_EDGES) return;
    int s = ei[e];
    int d = ei[N_EDGES + e];
    atomicAdd(&cd[d], 1);
    atomicAdd(&cb[edge_bin(pos, s, d)], 1);
}

// single block, 1024 threads, 32 elements each (32768 entries).
__global__ __launch_bounds__(1024) void scan_kernel(
    int* __restrict__ cursor, int* __restrict__ start)
{
    __shared__ int partial[1024];
    int tid = threadIdx.x;
    int base = tid * 32;
    int v[32];
    int s = 0;
    #pragma unroll
    for (int j = 0; j < 32; ++j) { v[j] = cursor[base + j]; s += v[j]; }
    partial[tid] = s;
    __syncthreads();
    for (int off = 1; off < 1024; off <<= 1) {
        int t = (tid >= off) ? partial[tid - off] : 0;
        __syncthreads();
        partial[tid] += t;
        __syncthreads();
    }
    int run = (tid > 0) ? partial[tid - 1] : 0;
    #pragma unroll
    for (int j = 0; j < 32; ++j) {
        start[base + j] = run;
        cursor[base + j] = run;
        run += v[j];
    }
    if (tid == 1023) start[32768] = run;
}

// ---------------- bin fill: binlist + inverse permutation ----------------
__global__ __launch_bounds__(256) void fill_bin_kernel(
    const int* __restrict__ ei, const float* __restrict__ pos,
    int* __restrict__ cb, int* __restrict__ binlist, int* __restrict__ epos)
{
    int e = blockIdx.x * blockDim.x + threadIdx.x;
    if (e >= N_EDGES) return;
    int s = ei[e];
    int d = ei[N_EDGES + e];
    int slot = atomicAdd(&cb[edge_bin(pos, s, d)], 1);
    binlist[slot] = e;
    epos[e] = slot;
}

// ---------------- Table build: W_eff[m][g][i][c] ------------------------
__global__ __launch_bounds__(256) void table_kernel(
    const float* __restrict__ Wt1, const float* __restrict__ Wt2,
    float* __restrict__ T)
{
    int entry = blockIdx.x;            // 0 .. 21*65-1
    int m = entry / 65;
    int g = entry - m * 65;
    float d0 = (float)g * (1.0f / TGRID);
    float d1 = d0 - 1.0f;
    int j0 = m - 1, j1 = m;
    const float sq20 = 4.47213595499958f;

    float f0 = 0.f, f1 = 0.f;
    if (j0 >= 0 && j0 < 20)
        f0 = 1.14136f * expf(2.0f - 1.0f/(1.0f + d0) - 1.0f/(1.0f - d0)) * sq20;
    if (j1 >= 0 && j1 < 20)
        f1 = 1.14136f * expf(2.0f - 1.0f/(1.0f + d1) - 1.0f/(1.0f - d1)) * sq20;
    j0 = j0 < 0 ? 0 : (j0 > 19 ? 19 : j0);
    j1 = j1 < 0 ? 0 : (j1 > 19 ? 19 : j1);

    __shared__ float h[64];
    int t = threadIdx.x;
    if (t < 64) {
        float a = fmaf(f0, Wt1[j0*64 + t], f1 * Wt1[j1*64 + t])
                  * 0.22360679774997896f;
        h[t] = 1.679177f * a / (1.0f + expf(-a));
    }
    __syncthreads();

    // sc = 1/8 (w norm) * 1/4 (inv) * 1/sqrt(8) (neighbor norm)
    const float sc = 0.011048543456039806f;
    for (int e2 = t; e2 < TENT; e2 += 256) {
        int i = e2 / 24;
        int c = e2 - i * 24;
        float v = 0.f;
        if (c < 22) {
            int widx = (c < 16) ? (i*16 + c)
                     : (c < 20) ? (256 + i*4 + (c - 16))
                                : (320 + i*2 + (c - 20));
            for (int k = 0; k < 64; ++k)
                v = fmaf(h[k], Wt2[k*352 + widx], v);
            v *= sc;
        }
        T[(size_t)entry * TENT + e2] = v;
    }
}

// ---------------- Kernel 3: binned per-edge lerp + contract --------------
// Thread handles edge binlist[idx]; a wave's 64 edges share 1-2 table rows
// (sorted by (m,g0)) so table loads broadcast. tp written at row idx
// (contiguous, whole row per thread -> coalesced, no sector RMW).
__global__ __launch_bounds__(256) void edge_table_binned(
    const float* __restrict__ pos, const int* __restrict__ ei,
    const float* __restrict__ T, const float* __restrict__ outp,
    const int* __restrict__ binlist,
    float* __restrict__ tp, int* __restrict__ cursor, int* __restrict__ elist)
{
    int idx = blockIdx.x * 256 + threadIdx.x;
    int e = binlist[idx];
    int src = ei[e];
    int dst = ei[N_EDGES + e];

    int slot = atomicAdd(&cursor[dst], 1);
    elist[slot] = e;

    float* trow = tp + (size_t)idx * TPW;   // binned layout

    float px = pos[dst*3+0] - pos[src*3+0];
    float py = pos[dst*3+1] - pos[src*3+1];
    float pz = pos[dst*3+2] - pos[src*3+2];
    float dist = sqrtf(px*px + py*py + pz*pz + 1e-12f);
    float rinv = 1.0f / dist;
    float ux = px*rinv, uy = py*rinv, uz = pz*rinv;

    float tt = dist * 4.2f;          // dist / (5/21)
    if (!(tt < 21.0f)) {             // out of radial range -> zero message
        float4 zz = make_float4(0.f, 0.f, 0.f, 0.f);
        #pragma unroll
        for (int q = 0; q < 9; ++q)
            *reinterpret_cast<float4*>(trow + q*4) = zz;
        trow[36] = 0.f; trow[37] = 0.f;
        return;
    }
    int m  = (int)tt;                // 0..20
    float d0 = tt - (float)m;
    float gf = d0 * (float)TGRID;
    int g0 = (int)gf; if (g0 > TGRID-1) g0 = TGRID-1;
    float fr = gf - (float)g0;

    const float4* r0 = (const float4*)(T + (size_t)(m*65 + g0) * TENT);
    const float4* r1 = r0 + (TENT/4);    // next d0 grid point (contiguous)

    float z[16];
    #pragma unroll
    for (int i = 0; i < 16; ++i) z[i] = outp[src*OUTC + i];

    float a0f[24], a1f[24];
    #pragma unroll
    for (int c = 0; c < 24; ++c) { a0f[c] = 0.f; a1f[c] = 0.f; }

    #pragma unroll
    for (int i = 0; i < 16; ++i) {
        float zi = z[i];
        #pragma unroll
        for (int q = 0; q < 6; ++q) {
            float4 v0 = r0[i*6 + q];
            float4 v1 = r1[i*6 + q];
            a0f[q*4+0] = fmaf(zi, v0.x, a0f[q*4+0]);
            a0f[q*4+1] = fmaf(zi, v0.y, a0f[q*4+1]);
            a0f[q*4+2] = fmaf(zi, v0.z, a0f[q*4+2]);
            a0f[q*4+3] = fmaf(zi, v0.w, a0f[q*4+3]);
            a1f[q*4+0] = fmaf(zi, v1.x, a1f[q*4+0]);
            a1f[q*4+1] = fmaf(zi, v1.y, a1f[q*4+1]);
            a1f[q*4+2] = fmaf(zi, v1.z, a1f[q*4+2]);
            a1f[q*4+3] = fmaf(zi, v1.w, a1f[q*4+3]);
        }
    }

    float vals[38];
    #pragma unroll
    for (int c = 0; c < 22; ++c)
        vals[c] = fmaf(fr, a1f[c] - a0f[c], a0f[c]);   // lerp in d0

    const float s3  = 1.7320508075688772f;
    const float s15 = 3.872983346207417f;
    const float s5  = 2.23606797749979f;
    float sh1x = s3*ux, sh1y = s3*uy, sh1z = s3*uz;
    float sh2a = s15 * ux * uz;
    float sh2b = s15 * ux * uy;
    float sh2c = s5 * (uy*uy - 0.5f*(ux*ux + uz*uz));
    float sh2d = s15 * uy * uz;
    float sh2e = 0.5f * s15 * (uz*uz - ux*ux);

    // expand T first (consumes vals[20..21]), then V descending (16..19)
    #pragma unroll
    for (int u = 1; u >= 0; --u) {
        float v = vals[20 + u];
        vals[28 + u*5 + 0] = v * sh2a;
        vals[28 + u*5 + 1] = v * sh2b;
        vals[28 + u*5 + 2] = v * sh2c;
        vals[28 + u*5 + 3] = v * sh2d;
        vals[28 + u*5 + 4] = v * sh2e;
    }
    #pragma unroll
    for (int u = 3; u >= 0; --u) {
        float v = vals[16 + u];
        vals[16 + u*3 + 0] = v * sh1x;
        vals[16 + u*3 + 1] = v * sh1y;
        vals[16 + u*3 + 2] = v * sh1z;
    }

    #pragma unroll
    for (int q = 0; q < 9; ++q)
        *reinterpret_cast<float4*>(trow + q*4) =
            make_float4(vals[q*4+0], vals[q*4+1], vals[q*4+2], vals[q*4+3]);
    trow[36] = vals[36];
    trow[37] = vals[37];
}

// ---------------- Kernel 4: gather segment-sum, SORTED (deterministic) ------
// Sort by edge id fixes the summation order; epos maps edge id -> binned
// tp row. Output bitwise deterministic regardless of atomic slot timing.
__global__ __launch_bounds__(256) void gather_sorted_kernel(
    const float* __restrict__ tp, const int* __restrict__ start,
    const int* __restrict__ elist, const int* __restrict__ epos,
    float* __restrict__ out)
{
    __shared__ int sb[4][128];
    __shared__ int so[4][128];
    int wave = threadIdx.x >> 6;
    int lane = threadIdx.x & 63;
    int n = blockIdx.x * 4 + wave;          // grid == N_NODES/4, always valid
    int s0 = start[n], s1 = start[n+1];
    int K = s1 - s0;
    bool small = (K <= 128);

    if (small) {
        for (int j = lane; j < K; j += 64) sb[wave][j] = elist[s0 + j];
    }
    __syncthreads();
    if (small) {
        for (int j = lane; j < K; j += 64) {
            int v = sb[wave][j];
            int r = 0;
            for (int q = 0; q < K; ++q) r += (sb[wave][q] < v);
            so[wave][r] = v;    // edge ids distinct -> r is a permutation
        }
    }
    __syncthreads();

    if (lane < 38) {
        float acc = 0.f;
        if (small) {
            for (int j = 0; j < K; ++j)
                acc += tp[(size_t)epos[so[wave][j]] * TPW + lane];
        } else {
            for (int j = s0; j < s1; ++j)
                acc += tp[(size_t)epos[elist[j]] * TPW + lane];
        }
        out[n*OUTC + 16 + lane] = acc;
    }
}

// ---------------- fallback (atomics) if ws too small -----------------
__global__ __launch_bounds__(256) void edge_kernel_atomic(
    const float* __restrict__ pos, const int* __restrict__ ei,
    const float* __restrict__ Wt1, const float* __restrict__ Wt2,
    float* out)
{
    int e = blockIdx.x * blockDim.x + threadIdx.x;
    if (e >= N_EDGES) return;
    int src = ei[e];
    int dst = ei[N_EDGES + e];
    float px = pos[dst*3+0] - pos[src*3+0];
    float py = pos[dst*3+1] - pos[src*3+1];
    float pz = pos[dst*3+2] - pos[src*3+2];
    float dist = sqrtf(px*px + py*py + pz*pz + 1e-12f);
    float rinv = 1.0f / dist;
    float ux = px*rinv, uy = py*rinv, uz = pz*rinv;
    const float step = 5.0f / 21.0f;
    float tt = dist / step;
    int m  = (int)floorf(tt);
    int j0 = m - 1, j1 = m;
    float d0 = tt - (float)m, d1 = d0 - 1.0f;
    const float sq20 = 4.47213595499958f;
    float f0 = 0.f, f1 = 0.f;
    if (j0 >= 0 && j0 < 20)
        f0 = 1.14136f * expf(2.0f - 1.0f/(1.0f + d0) - 1.0f/(1.0f - d0)) * sq20;
    if (j1 >= 0 && j1 < 20 && d1 > -1.0f)
        f1 = 1.14136f * expf(2.0f - 1.0f/(1.0f + d1) - 1.0f/(1.0f - d1)) * sq20;
    if (f0 == 0.f && f1 == 0.f) return;
    j0 = j0 < 0 ? 0 : (j0 > 19 ? 19 : j0);
    j1 = j1 < 0 ? 0 : (j1 > 19 ? 19 : j1);
    const float* w1a = Wt1 + j0*64;
    const float* w1b = Wt1 + j1*64;
    float z[16];
    #pragma unroll
    for (int i = 0; i < 16; ++i) z[i] = out[src*OUTC + i];
    const float rsq20 = 0.22360679774997896f;
    const float snorm = 1.679177f;
    float accS[16], accV[4], accT[2];
    #pragma unroll
    for (int u = 0; u < 16; ++u) accS[u] = 0.f;
    #pragma unroll
    for (int u = 0; u < 4; ++u) accV[u] = 0.f;
    #pragma unroll
    for (int u = 0; u < 2; ++u) accT[u] = 0.f;
    for (int k = 0; k < 64; ++k) {
        float a = fmaf(f0, w1a[k], f1 * w1b[k]) * rsq20;
        float hk = snorm * a / (1.0f + expf(-a));
        const float* row = Wt2 + k*352;
        float tmp[16];
        #pragma unroll
        for (int u = 0; u < 16; ++u) tmp[u] = 0.f;
        #pragma unroll
        for (int i = 0; i < 16; ++i) {
            float zi = z[i];
            #pragma unroll
            for (int u = 0; u < 16; ++u) tmp[u] = fmaf(zi, row[i*16 + u], tmp[u]);
        }
        #pragma unroll
        for (int u = 0; u < 16; ++u) accS[u] = fmaf(hk, tmp[u], accS[u]);
        float tv[4] = {0.f,0.f,0.f,0.f};
        #pragma unroll
        for (int i = 0; i < 16; ++i) {
            float zi = z[i];
            #pragma unroll
            for (int u = 0; u < 4; ++u) tv[u] = fmaf(zi, row[256 + i*4 + u], tv[u]);
        }
        #pragma unroll
        for (int u = 0; u < 4; ++u) accV[u] = fmaf(hk, tv[u], accV[u]);
        float tw[2] = {0.f,0.f};
        #pragma unroll
        for (int i = 0; i < 16; ++i) {
            float zi = z[i];
            #pragma unroll
            for (int u = 0; u < 2; ++u) tw[u] = fmaf(zi, row[320 + i*2 + u], tw[u]);
        }
        #pragma unroll
        for (int u = 0; u < 2; ++u) accT[u] = fmaf(hk, tw[u], accT[u]);
    }
    const float sc = 0.125f * 0.25f * 0.35355339059327373f;
    const float s3  = 1.7320508075688772f;
    const float s15 = 3.872983346207417f;
    const float s5  = 2.23606797749979f;
    float sh1x = s3*ux, sh1y = s3*uy, sh1z = s3*uz;
    float sh2[5];
    sh2[0] = s15 * ux * uz;
    sh2[1] = s15 * ux * uy;
    sh2[2] = s5 * (uy*uy - 0.5f*(ux*ux + uz*uz));
    sh2[3] = s15 * uy * uz;
    sh2[4] = 0.5f * s15 * (uz*uz - ux*ux);
    float* orow = out + dst*OUTC + 16;
    #pragma unroll
    for (int u = 0; u < 16; ++u) atomicAdd(&orow[u], accS[u] * sc);
    #pragma unroll
    for (int u = 0; u < 4; ++u) {
        float v = accV[u] * sc;
        atomicAdd(&orow[16 + u*3 + 0], v * sh1x);
        atomicAdd(&orow[16 + u*3 + 1], v * sh1y);
        atomicAdd(&orow[16 + u*3 + 2], v * sh1z);
    }
    #pragma unroll
    for (int u = 0; u < 2; ++u) {
        float v = accT[u] * sc;
        #pragma unroll
        for (int mm = 0; mm < 5; ++mm)
            atomicAdd(&orow[28 + u*5 + mm], v * sh2[mm]);
    }
}

extern "C" void kernel_launch(void* const* d_in, const int* in_sizes, int n_in,
                              void* d_out, int out_size, void* d_ws, size_t ws_size,
                              hipStream_t stream) {
    const float* x   = (const float*)d_in[0];
    const float* pos = (const float*)d_in[1];
    const int*   ei  = (const int*)d_in[2];
    const float* We1 = (const float*)d_in[3];
    const float* We2 = (const float*)d_in[4];
    const float* Wt1 = (const float*)d_in[5];
    const float* Wt2 = (const float*)d_in[6];
    float* out = (float*)d_out;

    char* base = (char*)d_ws;
    size_t off = 0;
    float* tp = (float*)(base + off);       off += (size_t)N_EDGES * TPW * 4;
    float* T  = (float*)(base + off);       off += (size_t)21 * 65 * TENT * 4;  // 2.1 MB
    int* cursor_dst = (int*)(base + off);   off += (size_t)32768 * 4;
    int* cursor_bin = (int*)(base + off);   off += (size_t)32768 * 4;   // adjacent: one memset
    int* start_dst  = (int*)(base + off);   off += (size_t)32769 * 4;
    int* start_bin  = (int*)(base + off);   off += (size_t)32769 * 4;
    int* elist   = (int*)(base + off);      off += (size_t)N_EDGES * 4;
    int* binlist = (int*)(base + off);      off += (size_t)N_EDGES * 4;
    int* epos    = (int*)(base + off);      off += (size_t)N_EDGES * 4;
    size_t need = off;

    node_emb_kernel<<<N_NODES/256, 256, 0, stream>>>(x, We1, We2, out);

    if (ws_size >= need) {
        table_kernel<<<21*65, 256, 0, stream>>>(Wt1, Wt2, T);
        hipMemsetAsync(cursor_dst, 0, (size_t)2 * 32768 * 4, stream);
        count_both_kernel<<<N_EDGES/256, 256, 0, stream>>>(ei, pos,
                                                           cursor_dst, cursor_bin);
        scan_kernel<<<1, 1024, 0, stream>>>(cursor_dst, start_dst);
        scan_kernel<<<1, 1024, 0, stream>>>(cursor_bin, start_bin);
        fill_bin_kernel<<<N_EDGES/256, 256, 0, stream>>>(ei, pos, cursor_bin,
                                                         binlist, epos);
        edge_table_binned<<<N_EDGES/256, 256, 0, stream>>>(pos, ei, T, out,
                                                           binlist, tp,
                                                           cursor_dst, elist);
        gather_sorted_kernel<<<N_NODES/4, 256, 0, stream>>>(tp, start_dst,
                                                            elist, epos, out);
    } else {
        hipMemsetAsync(out, 0, (size_t)out_size * sizeof(float), stream);
        node_emb_kernel<<<N_NODES/256, 256, 0, stream>>>(x, We1, We2, out);
        edge_kernel_atomic<<<N_EDGES/256, 256, 0, stream>>>(pos, ei, Wt1, Wt2, out);
    }
}

// Round 13
// 221.414 us; speedup vs baseline: 1.4231x; 1.3529x over previous
//
#include <hip/hip_runtime.h>
#include <math.h>

#define N_NODES 32768
#define N_EDGES 262144
#define OUTC 54      // 16 emb + 38 msg
#define TPW  40      // tp row stride in floats (38 used, 16B-aligned)
#define TGRID 64     // d0 samples per bin (65 points incl. both ends)
#define TENT 384     // floats per table entry: 16 i * 24 padded cols
#define NBINS 1345   // 21*64 in-range bins + 1 out-of-range bin

// ---------------- Kernel 1: node embeddings -----------------
__global__ __launch_bounds__(256) void node_emb_kernel(
    const float* __restrict__ x, const float* __restrict__ W1,
    const float* __restrict__ W2, float* __restrict__ out)
{
    int n = blockIdx.x * blockDim.x + threadIdx.x;
    if (n >= N_NODES) return;
    const float inv10 = 0.31622776601683794f;
    const float inv64 = 0.125f;

    float xr[10];
    #pragma unroll
    for (int i = 0; i < 10; ++i) xr[i] = x[n*10 + i];

    float t[64];
    #pragma unroll
    for (int k = 0; k < 64; ++k) {
        float acc = 0.f;
        #pragma unroll
        for (int i = 0; i < 10; ++i) acc = fmaf(xr[i], W1[i*64 + k], acc);
        t[k] = acc * inv10;
    }

    float e[16];
    #pragma unroll
    for (int j = 0; j < 16; ++j) e[j] = 0.f;
    #pragma unroll
    for (int k = 0; k < 64; ++k) {
        float tk = t[k];
        #pragma unroll
        for (int j = 0; j < 16; ++j) e[j] = fmaf(tk, W2[k*16 + j], e[j]);
    }
    #pragma unroll
    for (int j = 0; j < 16; ++j) out[n*OUTC + j] = e[j] * inv64;
}

// ---------------- bin function (shared by count & fill) ------------------
__device__ __forceinline__ int edge_bin(const float* __restrict__ pos,
                                        int src, int dst)
{
    float px = pos[dst*3+0] - pos[src*3+0];
    float py = pos[dst*3+1] - pos[src*3+1];
    float pz = pos[dst*3+2] - pos[src*3+2];
    float dist = sqrtf(px*px + py*py + pz*pz + 1e-12f);
    float tt = dist * 4.2f;
    if (!(tt < 21.0f)) return NBINS - 1;     // out-of-range bin
    int m = (int)tt;
    float gf = (tt - (float)m) * (float)TGRID;
    int g0 = (int)gf; if (g0 > TGRID-1) g0 = TGRID-1;
    return m * TGRID + g0;
}

// ---------------- count: LDS histogram (no hot global atomics) -----------
// Per-wave flush atomics hit 64 DISTINCT consecutive addresses -> no
// same-address serialization (round-12's 74us count was exactly that).
__global__ __launch_bounds__(256) void count_bins_kernel(
    const int* __restrict__ ei, const float* __restrict__ pos,
    int* __restrict__ cd, int* __restrict__ cb)
{
    __shared__ int hist[NBINS];
    for (int b = threadIdx.x; b < NBINS; b += 256) hist[b] = 0;
    __syncthreads();

    int e = blockIdx.x * 256 + threadIdx.x;
    int s = ei[e];
    int d = ei[N_EDGES + e];
    atomicAdd(&cd[d], 1);                    // 32k addresses: cheap (round 8)
    atomicAdd(&hist[edge_bin(pos, s, d)], 1);
    __syncthreads();

    for (int b = threadIdx.x; b < NBINS; b += 256) {
        int c = hist[b];
        if (c) atomicAdd(&cb[b], c);
    }
}

// single block, 1024 threads, 32 elements each (32768 entries).
__global__ __launch_bounds__(1024) void scan_kernel(
    int* __restrict__ cursor, int* __restrict__ start)
{
    __shared__ int partial[1024];
    int tid = threadIdx.x;
    int base = tid * 32;
    int v[32];
    int s = 0;
    #pragma unroll
    for (int j = 0; j < 32; ++j) { v[j] = cursor[base + j]; s += v[j]; }
    partial[tid] = s;
    __syncthreads();
    for (int off = 1; off < 1024; off <<= 1) {
        int t = (tid >= off) ? partial[tid - off] : 0;
        __syncthreads();
        partial[tid] += t;
        __syncthreads();
    }
    int run = (tid > 0) ? partial[tid - 1] : 0;
    #pragma unroll
    for (int j = 0; j < 32; ++j) {
        start[base + j] = run;
        cursor[base + j] = run;
        run += v[j];
    }
    if (tid == 1023) start[32768] = run;
}

// ---------------- fill: two-level (LDS hist -> range reserve -> rank) -----
__global__ __launch_bounds__(256) void fill_bins_kernel(
    const int* __restrict__ ei, const float* __restrict__ pos,
    int* __restrict__ cursor_bin,            // pre-scanned starts, consumed
    int* __restrict__ binlist, int* __restrict__ epos)
{
    __shared__ int hist[NBINS];
    __shared__ int rbase[NBINS];
    for (int b = threadIdx.x; b < NBINS; b += 256) hist[b] = 0;
    __syncthreads();

    int e = blockIdx.x * 256 + threadIdx.x;
    int s = ei[e];
    int d = ei[N_EDGES + e];
    int bin = edge_bin(pos, s, d);
    atomicAdd(&hist[bin], 1);
    __syncthreads();

    for (int b = threadIdx.x; b < NBINS; b += 256) {
        int c = hist[b];
        if (c) rbase[b] = atomicAdd(&cursor_bin[b], c);  // distinct addrs/wave
        hist[b] = 0;                                     // reuse as local cursor
    }
    __syncthreads();

    int lr = atomicAdd(&hist[bin], 1);       // LDS local rank
    int slot = rbase[bin] + lr;
    binlist[slot] = e;
    epos[e] = slot;
}

// ---------------- Table build: W_eff[m][g][i][c] ------------------------
__global__ __launch_bounds__(256) void table_kernel(
    const float* __restrict__ Wt1, const float* __restrict__ Wt2,
    float* __restrict__ T)
{
    int entry = blockIdx.x;            // 0 .. 21*65-1
    int m = entry / 65;
    int g = entry - m * 65;
    float d0 = (float)g * (1.0f / TGRID);
    float d1 = d0 - 1.0f;
    int j0 = m - 1, j1 = m;
    const float sq20 = 4.47213595499958f;

    float f0 = 0.f, f1 = 0.f;
    if (j0 >= 0 && j0 < 20)
        f0 = 1.14136f * expf(2.0f - 1.0f/(1.0f + d0) - 1.0f/(1.0f - d0)) * sq20;
    if (j1 >= 0 && j1 < 20)
        f1 = 1.14136f * expf(2.0f - 1.0f/(1.0f + d1) - 1.0f/(1.0f - d1)) * sq20;
    j0 = j0 < 0 ? 0 : (j0 > 19 ? 19 : j0);
    j1 = j1 < 0 ? 0 : (j1 > 19 ? 19 : j1);

    __shared__ float h[64];
    int t = threadIdx.x;
    if (t < 64) {
        float a = fmaf(f0, Wt1[j0*64 + t], f1 * Wt1[j1*64 + t])
                  * 0.22360679774997896f;
        h[t] = 1.679177f * a / (1.0f + expf(-a));
    }
    __syncthreads();

    // sc = 1/8 (w norm) * 1/4 (inv) * 1/sqrt(8) (neighbor norm)
    const float sc = 0.011048543456039806f;
    for (int e2 = t; e2 < TENT; e2 += 256) {
        int i = e2 / 24;
        int c = e2 - i * 24;
        float v = 0.f;
        if (c < 22) {
            int widx = (c < 16) ? (i*16 + c)
                     : (c < 20) ? (256 + i*4 + (c - 16))
                                : (320 + i*2 + (c - 20));
            for (int k = 0; k < 64; ++k)
                v = fmaf(h[k], Wt2[k*352 + widx], v);
            v *= sc;
        }
        T[(size_t)entry * TENT + e2] = v;
    }
}

// ---------------- Kernel 3: binned per-edge lerp + contract --------------
__global__ __launch_bounds__(256) void edge_table_binned(
    const float* __restrict__ pos, const int* __restrict__ ei,
    const float* __restrict__ T, const float* __restrict__ outp,
    const int* __restrict__ binlist,
    float* __restrict__ tp, int* __restrict__ cursor, int* __restrict__ elist)
{
    int idx = blockIdx.x * 256 + threadIdx.x;
    int e = binlist[idx];
    int src = ei[e];
    int dst = ei[N_EDGES + e];

    int slot = atomicAdd(&cursor[dst], 1);
    elist[slot] = e;

    float* trow = tp + (size_t)idx * TPW;   // binned layout

    float px = pos[dst*3+0] - pos[src*3+0];
    float py = pos[dst*3+1] - pos[src*3+1];
    float pz = pos[dst*3+2] - pos[src*3+2];
    float dist = sqrtf(px*px + py*py + pz*pz + 1e-12f);
    float rinv = 1.0f / dist;
    float ux = px*rinv, uy = py*rinv, uz = pz*rinv;

    float tt = dist * 4.2f;          // dist / (5/21)
    if (!(tt < 21.0f)) {             // out of radial range -> zero message
        float4 zz = make_float4(0.f, 0.f, 0.f, 0.f);
        #pragma unroll
        for (int q = 0; q < 9; ++q)
            *reinterpret_cast<float4*>(trow + q*4) = zz;
        trow[36] = 0.f; trow[37] = 0.f;
        return;
    }
    int m  = (int)tt;                // 0..20
    float d0 = tt - (float)m;
    float gf = d0 * (float)TGRID;
    int g0 = (int)gf; if (g0 > TGRID-1) g0 = TGRID-1;
    float fr = gf - (float)g0;

    const float4* r0 = (const float4*)(T + (size_t)(m*65 + g0) * TENT);
    const float4* r1 = r0 + (TENT/4);    // next d0 grid point (contiguous)

    float z[16];
    #pragma unroll
    for (int i = 0; i < 16; ++i) z[i] = outp[src*OUTC + i];

    float a0f[24], a1f[24];
    #pragma unroll
    for (int c = 0; c < 24; ++c) { a0f[c] = 0.f; a1f[c] = 0.f; }

    #pragma unroll
    for (int i = 0; i < 16; ++i) {
        float zi = z[i];
        #pragma unroll
        for (int q = 0; q < 6; ++q) {
            float4 v0 = r0[i*6 + q];
            float4 v1 = r1[i*6 + q];
            a0f[q*4+0] = fmaf(zi, v0.x, a0f[q*4+0]);
            a0f[q*4+1] = fmaf(zi, v0.y, a0f[q*4+1]);
            a0f[q*4+2] = fmaf(zi, v0.z, a0f[q*4+2]);
            a0f[q*4+3] = fmaf(zi, v0.w, a0f[q*4+3]);
            a1f[q*4+0] = fmaf(zi, v1.x, a1f[q*4+0]);
            a1f[q*4+1] = fmaf(zi, v1.y, a1f[q*4+1]);
            a1f[q*4+2] = fmaf(zi, v1.z, a1f[q*4+2]);
            a1f[q*4+3] = fmaf(zi, v1.w, a1f[q*4+3]);
        }
    }

    float vals[38];
    #pragma unroll
    for (int c = 0; c < 22; ++c)
        vals[c] = fmaf(fr, a1f[c] - a0f[c], a0f[c]);   // lerp in d0

    const float s3  = 1.7320508075688772f;
    const float s15 = 3.872983346207417f;
    const float s5  = 2.23606797749979f;
    float sh1x = s3*ux, sh1y = s3*uy, sh1z = s3*uz;
    float sh2a = s15 * ux * uz;
    float sh2b = s15 * ux * uy;
    float sh2c = s5 * (uy*uy - 0.5f*(ux*ux + uz*uz));
    float sh2d = s15 * uy * uz;
    float sh2e = 0.5f * s15 * (uz*uz - ux*ux);

    // expand T first (consumes vals[20..21]), then V descending (16..19)
    #pragma unroll
    for (int u = 1; u >= 0; --u) {
        float v = vals[20 + u];
        vals[28 + u*5 + 0] = v * sh2a;
        vals[28 + u*5 + 1] = v * sh2b;
        vals[28 + u*5 + 2] = v * sh2c;
        vals[28 + u*5 + 3] = v * sh2d;
        vals[28 + u*5 + 4] = v * sh2e;
    }
    #pragma unroll
    for (int u = 3; u >= 0; --u) {
        float v = vals[16 + u];
        vals[16 + u*3 + 0] = v * sh1x;
        vals[16 + u*3 + 1] = v * sh1y;
        vals[16 + u*3 + 2] = v * sh1z;
    }

    #pragma unroll
    for (int q = 0; q < 9; ++q)
        *reinterpret_cast<float4*>(trow + q*4) =
            make_float4(vals[q*4+0], vals[q*4+1], vals[q*4+2], vals[q*4+3]);
    trow[36] = vals[36];
    trow[37] = vals[37];
}

// ---------------- Kernel 4: gather segment-sum, SORTED (deterministic) ------
__global__ __launch_bounds__(256) void gather_sorted_kernel(
    const float* __restrict__ tp, const int* __restrict__ start,
    const int* __restrict__ elist, const int* __restrict__ epos,
    float* __restrict__ out)
{
    __shared__ int sb[4][128];
    __shared__ int so[4][128];
    int wave = threadIdx.x >> 6;
    int lane = threadIdx.x & 63;
    int n = blockIdx.x * 4 + wave;          // grid == N_NODES/4, always valid
    int s0 = start[n], s1 = start[n+1];
    int K = s1 - s0;
    bool small = (K <= 128);

    if (small) {
        for (int j = lane; j < K; j += 64) sb[wave][j] = elist[s0 + j];
    }
    __syncthreads();
    if (small) {
        for (int j = lane; j < K; j += 64) {
            int v = sb[wave][j];
            int r = 0;
            for (int q = 0; q < K; ++q) r += (sb[wave][q] < v);
            so[wave][r] = v;    // edge ids distinct -> r is a permutation
        }
    }
    __syncthreads();

    if (lane < 38) {
        float acc = 0.f;
        if (small) {
            for (int j = 0; j < K; ++j)
                acc += tp[(size_t)epos[so[wave][j]] * TPW + lane];
        } else {
            for (int j = s0; j < s1; ++j)
                acc += tp[(size_t)epos[elist[j]] * TPW + lane];
        }
        out[n*OUTC + 16 + lane] = acc;
    }
}

// ---------------- fallback (atomics) if ws too small -----------------
__global__ __launch_bounds__(256) void edge_kernel_atomic(
    const float* __restrict__ pos, const int* __restrict__ ei,
    const float* __restrict__ Wt1, const float* __restrict__ Wt2,
    float* out)
{
    int e = blockIdx.x * blockDim.x + threadIdx.x;
    if (e >= N_EDGES) return;
    int src = ei[e];
    int dst = ei[N_EDGES + e];
    float px = pos[dst*3+0] - pos[src*3+0];
    float py = pos[dst*3+1] - pos[src*3+1];
    float pz = pos[dst*3+2] - pos[src*3+2];
    float dist = sqrtf(px*px + py*py + pz*pz + 1e-12f);
    float rinv = 1.0f / dist;
    float ux = px*rinv, uy = py*rinv, uz = pz*rinv;
    const float step = 5.0f / 21.0f;
    float tt = dist / step;
    int m  = (int)floorf(tt);
    int j0 = m - 1, j1 = m;
    float d0 = tt - (float)m, d1 = d0 - 1.0f;
    const float sq20 = 4.47213595499958f;
    float f0 = 0.f, f1 = 0.f;
    if (j0 >= 0 && j0 < 20)
        f0 = 1.14136f * expf(2.0f - 1.0f/(1.0f + d0) - 1.0f/(1.0f - d0)) * sq20;
    if (j1 >= 0 && j1 < 20 && d1 > -1.0f)
        f1 = 1.14136f * expf(2.0f - 1.0f/(1.0f + d1) - 1.0f/(1.0f - d1)) * sq20;
    if (f0 == 0.f && f1 == 0.f) return;
    j0 = j0 < 0 ? 0 : (j0 > 19 ? 19 : j0);
    j1 = j1 < 0 ? 0 : (j1 > 19 ? 19 : j1);
    const float* w1a = Wt1 + j0*64;
    const float* w1b = Wt1 + j1*64;
    float z[16];
    #pragma unroll
    for (int i = 0; i < 16; ++i) z[i] = out[src*OUTC + i];
    const float rsq20 = 0.22360679774997896f;
    const float snorm = 1.679177f;
    float accS[16], accV[4], accT[2];
    #pragma unroll
    for (int u = 0; u < 16; ++u) accS[u] = 0.f;
    #pragma unroll
    for (int u = 0; u < 4; ++u) accV[u] = 0.f;
    #pragma unroll
    for (int u = 0; u < 2; ++u) accT[u] = 0.f;
    for (int k = 0; k < 64; ++k) {
        float a = fmaf(f0, w1a[k], f1 * w1b[k]) * rsq20;
        float hk = snorm * a / (1.0f + expf(-a));
        const float* row = Wt2 + k*352;
        float tmp[16];
        #pragma unroll
        for (int u = 0; u < 16; ++u) tmp[u] = 0.f;
        #pragma unroll
        for (int i = 0; i < 16; ++i) {
            float zi = z[i];
            #pragma unroll
            for (int u = 0; u < 16; ++u) tmp[u] = fmaf(zi, row[i*16 + u], tmp[u]);
        }
        #pragma unroll
        for (int u = 0; u < 16; ++u) accS[u] = fmaf(hk, tmp[u], accS[u]);
        float tv[4] = {0.f,0.f,0.f,0.f};
        #pragma unroll
        for (int i = 0; i < 16; ++i) {
            float zi = z[i];
            #pragma unroll
            for (int u = 0; u < 4; ++u) tv[u] = fmaf(zi, row[256 + i*4 + u], tv[u]);
        }
        #pragma unroll
        for (int u = 0; u < 4; ++u) accV[u] = fmaf(hk, tv[u], accV[u]);
        float tw[2] = {0.f,0.f};
        #pragma unroll
        for (int i = 0; i < 16; ++i) {
            float zi = z[i];
            #pragma unroll
            for (int u = 0; u < 2; ++u) tw[u] = fmaf(zi, row[320 + i*2 + u], tw[u]);
        }
        #pragma unroll
        for (int u = 0; u < 2; ++u) accT[u] = fmaf(hk, tw[u], accT[u]);
    }
    const float sc = 0.125f * 0.25f * 0.35355339059327373f;
    const float s3  = 1.7320508075688772f;
    const float s15 = 3.872983346207417f;
    const float s5  = 2.23606797749979f;
    float sh1x = s3*ux, sh1y = s3*uy, sh1z = s3*uz;
    float sh2[5];
    sh2[0] = s15 * ux * uz;
    sh2[1] = s15 * ux * uy;
    sh2[2] = s5 * (uy*uy - 0.5f*(ux*ux + uz*uz));
    sh2[3] = s15 * uy * uz;
    sh2[4] = 0.5f * s15 * (uz*uz - ux*ux);
    float* orow = out + dst*OUTC + 16;
    #pragma unroll
    for (int u = 0; u < 16; ++u) atomicAdd(&orow[u], accS[u] * sc);
    #pragma unroll
    for (int u = 0; u < 4; ++u) {
        float v = accV[u] * sc;
        atomicAdd(&orow[16 + u*3 + 0], v * sh1x);
        atomicAdd(&orow[16 + u*3 + 1], v * sh1y);
        atomicAdd(&orow[16 + u*3 + 2], v * sh1z);
    }
    #pragma unroll
    for (int u = 0; u < 2; ++u) {
        float v = accT[u] * sc;
        #pragma unroll
        for (int mm = 0; mm < 5; ++mm)
            atomicAdd(&orow[28 + u*5 + mm], v * sh2[mm]);
    }
}

extern "C" void kernel_launch(void* const* d_in, const int* in_sizes, int n_in,
                              void* d_out, int out_size, void* d_ws, size_t ws_size,
                              hipStream_t stream) {
    const float* x   = (const float*)d_in[0];
    const float* pos = (const float*)d_in[1];
    const int*   ei  = (const int*)d_in[2];
    const float* We1 = (const float*)d_in[3];
    const float* We2 = (const float*)d_in[4];
    const float* Wt1 = (const float*)d_in[5];
    const float* Wt2 = (const float*)d_in[6];
    float* out = (float*)d_out;

    char* base = (char*)d_ws;
    size_t off = 0;
    float* tp = (float*)(base + off);       off += (size_t)N_EDGES * TPW * 4;
    float* T  = (float*)(base + off);       off += (size_t)21 * 65 * TENT * 4;  // 2.1 MB
    int* cursor_dst = (int*)(base + off);   off += (size_t)32768 * 4;
    int* cursor_bin = (int*)(base + off);   off += (size_t)32768 * 4;   // adjacent: one memset
    int* start_dst  = (int*)(base + off);   off += (size_t)32769 * 4;
    int* start_bin  = (int*)(base + off);   off += (size_t)32769 * 4;
    int* elist   = (int*)(base + off);      off += (size_t)N_EDGES * 4;
    int* binlist = (int*)(base + off);      off += (size_t)N_EDGES * 4;
    int* epos    = (int*)(base + off);      off += (size_t)N_EDGES * 4;
    size_t need = off;

    node_emb_kernel<<<N_NODES/256, 256, 0, stream>>>(x, We1, We2, out);

    if (ws_size >= need) {
        table_kernel<<<21*65, 256, 0, stream>>>(Wt1, Wt2, T);
        hipMemsetAsync(cursor_dst, 0, (size_t)2 * 32768 * 4, stream);
        count_bins_kernel<<<N_EDGES/256, 256, 0, stream>>>(ei, pos,
                                                           cursor_dst, cursor_bin);
        scan_kernel<<<1, 1024, 0, stream>>>(cursor_dst, start_dst);
        scan_kernel<<<1, 1024, 0, stream>>>(cursor_bin, start_bin);
        fill_bins_kernel<<<N_EDGES/256, 256, 0, stream>>>(ei, pos, cursor_bin,
                                                          binlist, epos);
        edge_table_binned<<<N_EDGES/256, 256, 0, stream>>>(pos, ei, T, out,
                                                           binlist, tp,
                                                           cursor_dst, elist);
        gather_sorted_kernel<<<N_NODES/4, 256, 0, stream>>>(tp, start_dst,
                                                            elist, epos, out);
    } else {
        hipMemsetAsync(out, 0, (size_t)out_size * sizeof(float), stream);
        node_emb_kernel<<<N_NODES/256, 256, 0, stream>>>(x, We1, We2, out);
        edge_kernel_atomic<<<N_EDGES/256, 256, 0, stream>>>(pos, ei, Wt1, Wt2, out);
    }
}